// Round 3
// baseline (736.198 us; speedup 1.0000x reference)
//
#include <hip/hip_runtime.h>
#include <stdint.h>

#define NN 8192
#define DD 128

typedef __attribute__((ext_vector_type(4))) float floatx4;
typedef __attribute__((ext_vector_type(8))) short s16x8;
typedef __attribute__((ext_vector_type(8))) unsigned short u16x8;
typedef __attribute__((ext_vector_type(4))) unsigned short u16x4;

__device__ inline unsigned short f32_bf16(float f) {
    union { float f; uint32_t u; } v; v.f = f;
    uint32_t u = v.u;
    return (unsigned short)((u + 0x7FFFu + ((u >> 16) & 1u)) >> 16);
}

// async global->LDS, 16 bytes per lane. LDS dest is wave-uniform base + lane*16.
__device__ inline void gld16(const unsigned short* g, unsigned short* l) {
    __builtin_amdgcn_global_load_lds(
        (const __attribute__((address_space(1))) void*)g,
        (__attribute__((address_space(3))) void*)l, 16, 0, 0);
}

// ---------------------------------------------------------------------------
// convert_fused: src fp32 [R][C] ->
//   dstT bf16 [C][R] (transposed)   if dstT != null
//   dstN bf16 [R][C]                if dstN != null
//   rsum[r] += row sums (fp32)      if rsum != null   (atomic)
//   csum[c] += col sums (fp32)      if csum != null   (atomic)
// Tile 64x64, block=256. Grid: x = COLUMN tile (fast), y = ROW tile.
// ---------------------------------------------------------------------------
__global__ __launch_bounds__(256) void convert_fused(const float* __restrict__ src,
        unsigned short* __restrict__ dstT, unsigned short* __restrict__ dstN,
        int R, int C, float* __restrict__ rsum, float* __restrict__ csum) {
    __shared__ __align__(16) unsigned short lt[64 * 68];
    __shared__ float colbuf[64];
    int c0 = blockIdx.x * 64, r0 = blockIdx.y * 64;
    int t = threadIdx.x, tx = t & 15, ty = t >> 4;
    if (csum && t < 64) colbuf[t] = 0.f;

    const float* sp = src + (size_t)(r0 + ty * 4) * C + c0 + tx * 4;
    float f[4][4];
#pragma unroll
    for (int i = 0; i < 4; ++i) {
        floatx4 v = *(const floatx4*)(sp + (size_t)i * C);
        f[i][0] = v[0]; f[i][1] = v[1]; f[i][2] = v[2]; f[i][3] = v[3];
    }
    if (dstN) {
#pragma unroll
        for (int i = 0; i < 4; ++i) {
            u16x4 pk;
#pragma unroll
            for (int j = 0; j < 4; ++j) pk[j] = f32_bf16(f[i][j]);
            *(u16x4*)(dstN + (size_t)(r0 + ty * 4 + i) * C + c0 + tx * 4) = pk;
        }
    }
    if (rsum) {
#pragma unroll
        for (int i = 0; i < 4; ++i) {
            float s = (f[i][0] + f[i][1]) + (f[i][2] + f[i][3]);
            s += __shfl_down(s, 8, 16);
            s += __shfl_down(s, 4, 16);
            s += __shfl_down(s, 2, 16);
            s += __shfl_down(s, 1, 16);
            if (tx == 0) atomicAdd(&rsum[r0 + ty * 4 + i], s);
        }
    }
    __syncthreads();   // colbuf init visible
    if (csum) {
#pragma unroll
        for (int j = 0; j < 4; ++j) {
            float s = (f[0][j] + f[1][j]) + (f[2][j] + f[3][j]);
            s += __shfl_down(s, 32);
            s += __shfl_down(s, 16);
            if (((t >> 4) & 3) == 0) atomicAdd(&colbuf[tx * 4 + j], s);
        }
    }
    if (dstT) {
#pragma unroll
        for (int j = 0; j < 4; ++j) {
            u16x4 pk;
#pragma unroll
            for (int i = 0; i < 4; ++i) pk[i] = f32_bf16(f[i][j]);
            *(u16x4*)(&lt[(tx * 4 + j) * 68 + ty * 4]) = pk;
        }
    }
    __syncthreads();
    if (csum && t < 64) atomicAdd(&csum[c0 + t], colbuf[t]);
    if (dstT) {
        int cc = t >> 2, seg = t & 3;
        u16x4 q0 = *(const u16x4*)(&lt[cc * 68 + seg * 16]);
        u16x4 q1 = *(const u16x4*)(&lt[cc * 68 + seg * 16 + 4]);
        u16x4 q2 = *(const u16x4*)(&lt[cc * 68 + seg * 16 + 8]);
        u16x4 q3 = *(const u16x4*)(&lt[cc * 68 + seg * 16 + 12]);
        u16x8 o0, o1;
#pragma unroll
        for (int e = 0; e < 4; ++e) { o0[e] = q0[e]; o0[4 + e] = q1[e];
                                      o1[e] = q2[e]; o1[4 + e] = q3[e]; }
        unsigned short* dp = dstT + (size_t)(c0 + cc) * R + r0 + seg * 16;
        *(u16x8*)dp = o0;
        *(u16x8*)(dp + 8) = o1;
    }
}

// ---------------------------------------------------------------------------
// gemm_big_bf16: Ypart[bz][m][n] = A[m, kslice] @ B[kslice, n]
//   A bf16 row-major [m][k] (ld=NN), B bf16 transposed Bt[n=128][k=NN].
// split-K = 8, BM=BN=128, BK=64, block=256 (4 waves, 2x2).
// 2-phase double-buffered pipeline: prefetch of tile t+1 is issued BEFORE
// the ds_read+MFMA of tile t, so the 32 KB/step HBM stream stays in flight
// under compute. One barrier (vmcnt+lgkm drain) per K-step. XOR-swizzle on
// both sides (inverse-swizzled global source + swizzled ds_read_b128).
// ---------------------------------------------------------------------------
__global__ __launch_bounds__(256, 2) void gemm_big_bf16(
        const unsigned short* __restrict__ A16,
        const unsigned short* __restrict__ Bt, float* __restrict__ Ypart) {
    __shared__ __align__(16) unsigned short LA[2 * 128 * 64];
    __shared__ __align__(16) unsigned short LB[2 * 128 * 64];
    int m0 = blockIdx.x * 128;
    int kbase = blockIdx.y * (NN / 8);
    int t = threadIdx.x;
    int w = t >> 6, lane = t & 63;
    int wy = w >> 1, wx = w & 1;
    int l15 = lane & 15, l4 = lane >> 4;
    int mrow = lane >> 3;                 // row within 8-row chunk (== m&7)
    int kj = ((lane & 7) ^ mrow) * 8;     // inverse-swizzled k offset (shorts)

    const unsigned short* ag[4];
    const unsigned short* bg[4];
    int lo[4];
#pragma unroll
    for (int i = 0; i < 4; ++i) {
        int chunk = i * 4 + w;            // 16 chunks of 8 rows
        int row = chunk * 8 + mrow;       // 0..127
        ag[i] = A16 + (size_t)(m0 + row) * NN + kbase + kj;
        bg[i] = Bt + (size_t)row * NN + kbase + kj;
        lo[i] = chunk * 512;              // wave-uniform LDS base (shorts)
    }
    floatx4 acc[4][4] = {};

    // prologue: stage tile 0 into buffer 0
#pragma unroll
    for (int i = 0; i < 4; ++i) { gld16(ag[i], &LA[lo[i]]); gld16(bg[i], &LB[lo[i]]); }
    __syncthreads();

    int cur = 0;
    for (int kt = 0; kt < 16; ++kt) {
        if (kt < 15) {                    // issue next-tile loads FIRST
            int off = (kt + 1) * 64;
            int nb = (cur ^ 1) << 13;     // *8192 shorts
#pragma unroll
            for (int i = 0; i < 4; ++i) {
                gld16(ag[i] + off, &LA[nb + lo[i]]);
                gld16(bg[i] + off, &LB[nb + lo[i]]);
            }
        }
        int cb = cur << 13;
#pragma unroll
        for (int ks = 0; ks < 2; ++ks) {
            s16x8 af[4], bfr[4];
#pragma unroll
            for (int i = 0; i < 4; ++i) {
                int m = wy * 64 + i * 16 + l15;
                int kb = ks * 4 + l4;
                af[i] = *(const s16x8*)(&LA[cb + m * 64 + ((kb ^ (m & 7)) * 8)]);
                int n = wx * 64 + i * 16 + l15;
                bfr[i] = *(const s16x8*)(&LB[cb + n * 64 + ((kb ^ (n & 7)) * 8)]);
            }
#pragma unroll
            for (int i = 0; i < 4; ++i)
#pragma unroll
                for (int j = 0; j < 4; ++j)
                    acc[i][j] = __builtin_amdgcn_mfma_f32_16x16x32_bf16(
                        af[i], bfr[j], acc[i][j], 0, 0, 0);
        }
        __syncthreads();                  // drains vmcnt (next tile resident)
        cur ^= 1;
    }
    float* Y = Ypart + (size_t)blockIdx.y * ((size_t)NN * DD);
#pragma unroll
    for (int i = 0; i < 4; ++i)
#pragma unroll
        for (int j = 0; j < 4; ++j) {
            int col = wx * 64 + j * 16 + l15;
#pragma unroll
            for (int r = 0; r < 4; ++r) {
                int row = wy * 64 + i * 16 + l4 * 4 + r;
                Y[(size_t)(m0 + row) * DD + col] = acc[i][j][r];
            }
        }
}

// ---------------------------------------------------------------------------
// gemm_big fallback (fp32 source), AMODE 1: fp32 row-major; AMODE 2: fp32
// [k][m] transposed staging. Only used when workspace is too small.
// ---------------------------------------------------------------------------
template <int AMODE>
__global__ __launch_bounds__(256, 2) void gemm_big(const void* __restrict__ Av,
        const unsigned short* __restrict__ Bt, float* __restrict__ Ypart) {
    __shared__ __align__(16) unsigned short LA[128 * 72];
    __shared__ __align__(16) unsigned short LB[128 * 72];
    int m0 = blockIdx.x * 128;
    int kbase = blockIdx.y * (NN / 8);
    int t = threadIdx.x;
    int wid = t >> 6, lane = t & 63;
    int wy = wid >> 1, wx = wid & 1;
    int l15 = lane & 15, l4 = lane >> 4;
    floatx4 acc[4][4] = {};

    for (int kt = 0; kt < NN / 8; kt += 64) {
        int k0 = kbase + kt;
        if (AMODE == 1) {
            const float* A32 = (const float*)Av;
            int m = t >> 4, kk = (t & 15) * 4;
#pragma unroll
            for (int s = 0; s < 8; ++s) {
                int mm = m + s * 16;
                floatx4 f = *(const floatx4*)(A32 + (size_t)(m0 + mm) * NN + k0 + kk);
                u16x4 pk;
#pragma unroll
                for (int e = 0; e < 4; ++e) pk[e] = f32_bf16(f[e]);
                *(u16x4*)(&LA[mm * 72 + kk]) = pk;
            }
        } else {
            const float* A32 = (const float*)Av;
            int kr = t >> 5, mm = (t & 31) * 4;
#pragma unroll
            for (int s = 0; s < 8; ++s) {
                int kk = kr + s * 8;
                floatx4 f = *(const floatx4*)(A32 + (size_t)(k0 + kk) * NN + m0 + mm);
#pragma unroll
                for (int e = 0; e < 4; ++e) LA[(mm + e) * 72 + kk] = f32_bf16(f[e]);
            }
        }
        {
            int n = t >> 3, kk = (t & 7) * 8;
#pragma unroll
            for (int s = 0; s < 4; ++s) {
                int nn = n + s * 32;
                u16x8 d = *(const u16x8*)(Bt + (size_t)nn * NN + k0 + kk);
                *(u16x8*)(&LB[nn * 72 + kk]) = d;
            }
        }
        __syncthreads();
#pragma unroll
        for (int ks = 0; ks < 2; ++ks) {
            s16x8 af[4], bfr[4];
#pragma unroll
            for (int i = 0; i < 4; ++i) {
                int m = wy * 64 + i * 16 + l15;
                af[i] = *(const s16x8*)(&LA[m * 72 + ks * 32 + l4 * 8]);
                int n = wx * 64 + i * 16 + l15;
                bfr[i] = *(const s16x8*)(&LB[n * 72 + ks * 32 + l4 * 8]);
            }
#pragma unroll
            for (int i = 0; i < 4; ++i)
#pragma unroll
                for (int j = 0; j < 4; ++j)
                    acc[i][j] = __builtin_amdgcn_mfma_f32_16x16x32_bf16(
                        af[i], bfr[j], acc[i][j], 0, 0, 0);
        }
        __syncthreads();
    }
    float* Y = Ypart + (size_t)blockIdx.y * ((size_t)NN * DD);
#pragma unroll
    for (int i = 0; i < 4; ++i)
#pragma unroll
        for (int j = 0; j < 4; ++j) {
            int col = wx * 64 + j * 16 + l15;
#pragma unroll
            for (int r = 0; r < 4; ++r) {
                int row = wy * 64 + i * 16 + l4 * 4 + r;
                Y[(size_t)(m0 + row) * DD + col] = acc[i][j][r];
            }
        }
}

// ---------------------------------------------------------------------------
// gemm_small: Z[m][n] = (sum_s Ypart[s][m][:]) @ W  * (1/sums[m])
//   writes out32 fp32 [NN][DD] (if non-null) and/or outT bf16 [DD][NN].
// BM=32, k=128 (one staged tile), grid = NN/32 = 256, block=256 (1 blk/CU).
// outT path transposes through LDS (stride 40 shorts = 80 B, 16-B aligned)
// so global stores are 16-B dense.
// ---------------------------------------------------------------------------
__global__ __launch_bounds__(256) void gemm_small(const float* __restrict__ Ypart,
        const unsigned short* __restrict__ Wt, const float* __restrict__ sums,
        float* __restrict__ out32, unsigned short* __restrict__ outT) {
    __shared__ __align__(16) unsigned short LA[128 * 40];   // staging [32*136] / LT [128*40]
    __shared__ __align__(16) unsigned short LB[128 * 136];
    int m0 = blockIdx.x * 32;
    int t = threadIdx.x;
    {
        int m = t >> 3, kk = (t & 7) * 4;
#pragma unroll
        for (int e = 0; e < 4; ++e) {
            floatx4 sum = {0.f, 0.f, 0.f, 0.f};
#pragma unroll
            for (int s = 0; s < 8; ++s)
                sum += *(const floatx4*)(Ypart + (size_t)s * ((size_t)NN * DD) +
                                         (size_t)(m0 + m) * DD + kk + e * 32);
            u16x4 pk;
#pragma unroll
            for (int e2 = 0; e2 < 4; ++e2) pk[e2] = f32_bf16(sum[e2]);
            *(u16x4*)(&LA[m * 136 + kk + e * 32]) = pk;
        }
        int n = t >> 1, k8 = (t & 1) * 64;
#pragma unroll
        for (int s = 0; s < 8; ++s)
            *(u16x8*)(&LB[n * 136 + k8 + s * 8]) =
                *(const u16x8*)(Wt + n * 128 + k8 + s * 8);
    }
    __syncthreads();
    int wid = t >> 6, lane = t & 63;
    int wy = wid >> 1, wx = wid & 1, l15 = lane & 15, l4 = lane >> 4;
    floatx4 acc[4] = {};
#pragma unroll
    for (int ks = 0; ks < 4; ++ks) {
        s16x8 af = *(const s16x8*)(&LA[(wy * 16 + l15) * 136 + ks * 32 + l4 * 8]);
#pragma unroll
        for (int j = 0; j < 4; ++j) {
            s16x8 bfr = *(const s16x8*)(&LB[(wx * 64 + j * 16 + l15) * 136 + ks * 32 + l4 * 8]);
            acc[j] = __builtin_amdgcn_mfma_f32_16x16x32_bf16(af, bfr, acc[j], 0, 0, 0);
        }
    }
    if (out32) {
#pragma unroll
        for (int j = 0; j < 4; ++j) {
            int col = wx * 64 + j * 16 + l15;
#pragma unroll
            for (int r = 0; r < 4; ++r) {
                int row = wy * 16 + l4 * 4 + r;
                int m = m0 + row;
                out32[(size_t)m * DD + col] = acc[j][r] / sums[m];
            }
        }
    }
    if (outT) {
        __syncthreads();                          // LA (af source) now dead
        unsigned short* LT = LA;                  // [128 cols][stride 40]
#pragma unroll
        for (int j = 0; j < 4; ++j) {
            int col = wx * 64 + j * 16 + l15;
#pragma unroll
            for (int r = 0; r < 4; ++r) {
                int row = wy * 16 + l4 * 4 + r;
                LT[col * 40 + row] = f32_bf16(acc[j][r] / sums[m0 + row]);
            }
        }
        __syncthreads();
        int col = t >> 1, half = t & 1;
        u16x8 v0 = *(const u16x8*)(&LT[col * 40 + half * 16]);
        u16x8 v1 = *(const u16x8*)(&LT[col * 40 + half * 16 + 8]);
        unsigned short* dp = outT + (size_t)col * NN + m0 + half * 16;
        *(u16x8*)dp = v0;
        *(u16x8*)(dp + 8) = v1;
    }
}

// ---------------------------------------------------------------------------
extern "C" void kernel_launch(void* const* d_in, const int* in_sizes, int n_in,
                              void* d_out, int out_size, void* d_ws, size_t ws_size,
                              hipStream_t stream) {
    const float* adj = (const float*)d_in[0];
    const float* uni = (const float*)d_in[1];
    const float* sub = (const float*)d_in[2];
    const float* ws1 = (const float*)d_in[3];
    const float* wu1 = (const float*)d_in[4];
    float* out = (float*)d_out;

    const size_t SZ_A16 = (size_t)NN * NN * 2;       // 128 MiB
    const size_t SZ_Y   = (size_t)8 * NN * DD * 4;   // 32 MiB (8 split-K slices)
    const size_t SZ_F   = (size_t)NN * DD * 2;       // 2 MiB
    const size_t SZ_W   = (size_t)128 * 128 * 2;
    const size_t SZ_V   = (size_t)NN * 4;

    size_t needA = 2 * SZ_A16 + SZ_Y + 6 * SZ_F + 2 * SZ_W + 2 * SZ_V;
    size_t needB = 1 * SZ_A16 + SZ_Y + 6 * SZ_F + 2 * SZ_W + 2 * SZ_V;
    int tier = (ws_size >= needA) ? 0 : ((ws_size >= needB) ? 1 : 2);

    char* p = (char*)d_ws;
    unsigned short* A16 = nullptr;
    unsigned short* AT16 = nullptr;
    if (tier == 0) { A16 = (unsigned short*)p; p += SZ_A16; }
    if (tier <= 1) { AT16 = (unsigned short*)p; p += SZ_A16; }
    float* Ypart = (float*)p; p += SZ_Y;
    unsigned short* F[6];
    for (int i = 0; i < 6; ++i) { F[i] = (unsigned short*)p; p += SZ_F; }
    unsigned short* Wst = (unsigned short*)p; p += SZ_W;
    unsigned short* Wut = (unsigned short*)p; p += SZ_W;
    float* rsum = (float*)p; p += SZ_V;
    float* csum = (float*)p; p += SZ_V;

    // --- preprocessing: one pass over adj does convert(s) + row/col sums ---
    // NOTE: convert grid is (x = C/64 column tiles, y = R/64 row tiles).
    hipMemsetAsync(rsum, 0, 2 * SZ_V, stream);   // rsum & csum contiguous
    if (tier == 0)
        convert_fused<<<dim3(128, 128), 256, 0, stream>>>(adj, AT16, A16, NN, NN, rsum, csum);
    else if (tier == 1)
        convert_fused<<<dim3(128, 128), 256, 0, stream>>>(adj, AT16, nullptr, NN, NN, rsum, csum);
    else
        convert_fused<<<dim3(128, 128), 256, 0, stream>>>(adj, nullptr, nullptr, NN, NN, rsum, csum);
    convert_fused<<<dim3(2, 128), 256, 0, stream>>>(uni, F[0], nullptr, NN, DD, nullptr, nullptr);
    convert_fused<<<dim3(2, 128), 256, 0, stream>>>(sub, F[1], nullptr, NN, DD, nullptr, nullptr);
    convert_fused<<<dim3(2, 2), 256, 0, stream>>>(ws1, Wst, nullptr, DD, DD, nullptr, nullptr);
    convert_fused<<<dim3(2, 2), 256, 0, stream>>>(wu1, Wut, nullptr, DD, DD, nullptr, nullptr);

    unsigned short* Ut[3] = {F[0], F[3], F[5]};
    unsigned short* St[3] = {F[1], F[2], F[4]};

    for (int pass = 0; pass < 3; ++pass) {
        // G2: Ys = adjT @ U_prev  (normalize by colsum, then @ w_s1)
        if (tier <= 1)
            gemm_big_bf16<<<dim3(64, 8), 256, 0, stream>>>(AT16, Ut[pass], Ypart);
        else
            gemm_big<2><<<dim3(64, 8), 256, 0, stream>>>(adj, Ut[pass], Ypart);
        if (pass < 2)
            gemm_small<<<256, 256, 0, stream>>>(Ypart, Wst, csum, nullptr, St[pass + 1]);
        else
            gemm_small<<<256, 256, 0, stream>>>(Ypart, Wst, csum, out, nullptr);

        // G1: Yu = adj @ S_prev  (normalize by rowsum, then @ w_u1)
        if (tier == 0)
            gemm_big_bf16<<<dim3(64, 8), 256, 0, stream>>>(A16, St[pass], Ypart);
        else
            gemm_big<1><<<dim3(64, 8), 256, 0, stream>>>(adj, St[pass], Ypart);
        if (pass < 2)
            gemm_small<<<256, 256, 0, stream>>>(Ypart, Wut, rsum, nullptr, Ut[pass + 1]);
        else
            gemm_small<<<256, 256, 0, stream>>>(Ypart, Wut, rsum, out + (size_t)NN * DD, nullptr);
    }
}

// Round 4
// 710.883 us; speedup vs baseline: 1.0356x; 1.0356x over previous
//
#include <hip/hip_runtime.h>
#include <stdint.h>

#define NN 8192
#define DD 128

typedef __attribute__((ext_vector_type(4))) float floatx4;
typedef __attribute__((ext_vector_type(8))) short s16x8;
typedef __attribute__((ext_vector_type(8))) unsigned short u16x8;
typedef __attribute__((ext_vector_type(4))) unsigned short u16x4;

__device__ inline unsigned short f32_bf16(float f) {
    union { float f; uint32_t u; } v; v.f = f;
    uint32_t u = v.u;
    return (unsigned short)((u + 0x7FFFu + ((u >> 16) & 1u)) >> 16);
}

// async global->LDS, 16 bytes per lane. LDS dest is wave-uniform base + lane*16.
__device__ inline void gld16(const unsigned short* g, unsigned short* l) {
    __builtin_amdgcn_global_load_lds(
        (const __attribute__((address_space(1))) void*)g,
        (__attribute__((address_space(3))) void*)l, 16, 0, 0);
}

// ---------------------------------------------------------------------------
// convert_fused: src fp32 [R][C] ->
//   dstT bf16 [C][R] (transposed)   if dstT != null
//   dstN bf16 [R][C]                if dstN != null
//   rsum[r] += row sums (fp32)      if rsum != null   (atomic)
//   csum[c] += col sums (fp32)      if csum != null   (atomic)
// Tile 64x64, block=256. Grid: x = COLUMN tile (fast), y = ROW tile.
// ---------------------------------------------------------------------------
__global__ __launch_bounds__(256) void convert_fused(const float* __restrict__ src,
        unsigned short* __restrict__ dstT, unsigned short* __restrict__ dstN,
        int R, int C, float* __restrict__ rsum, float* __restrict__ csum) {
    __shared__ __align__(16) unsigned short lt[64 * 68];
    __shared__ float colbuf[64];
    int c0 = blockIdx.x * 64, r0 = blockIdx.y * 64;
    int t = threadIdx.x, tx = t & 15, ty = t >> 4;
    if (csum && t < 64) colbuf[t] = 0.f;

    const float* sp = src + (size_t)(r0 + ty * 4) * C + c0 + tx * 4;
    float f[4][4];
#pragma unroll
    for (int i = 0; i < 4; ++i) {
        floatx4 v = *(const floatx4*)(sp + (size_t)i * C);
        f[i][0] = v[0]; f[i][1] = v[1]; f[i][2] = v[2]; f[i][3] = v[3];
    }
    if (dstN) {
#pragma unroll
        for (int i = 0; i < 4; ++i) {
            u16x4 pk;
#pragma unroll
            for (int j = 0; j < 4; ++j) pk[j] = f32_bf16(f[i][j]);
            *(u16x4*)(dstN + (size_t)(r0 + ty * 4 + i) * C + c0 + tx * 4) = pk;
        }
    }
    if (rsum) {
#pragma unroll
        for (int i = 0; i < 4; ++i) {
            float s = (f[i][0] + f[i][1]) + (f[i][2] + f[i][3]);
            s += __shfl_down(s, 8, 16);
            s += __shfl_down(s, 4, 16);
            s += __shfl_down(s, 2, 16);
            s += __shfl_down(s, 1, 16);
            if (tx == 0) atomicAdd(&rsum[r0 + ty * 4 + i], s);
        }
    }
    __syncthreads();   // colbuf init visible
    if (csum) {
#pragma unroll
        for (int j = 0; j < 4; ++j) {
            float s = (f[0][j] + f[1][j]) + (f[2][j] + f[3][j]);
            s += __shfl_down(s, 32);
            s += __shfl_down(s, 16);
            if (((t >> 4) & 3) == 0) atomicAdd(&colbuf[tx * 4 + j], s);
        }
    }
    if (dstT) {
#pragma unroll
        for (int j = 0; j < 4; ++j) {
            u16x4 pk;
#pragma unroll
            for (int i = 0; i < 4; ++i) pk[i] = f32_bf16(f[i][j]);
            *(u16x4*)(&lt[(tx * 4 + j) * 68 + ty * 4]) = pk;
        }
    }
    __syncthreads();
    if (csum && t < 64) atomicAdd(&csum[c0 + t], colbuf[t]);
    if (dstT) {
        int cc = t >> 2, seg = t & 3;
        u16x4 q0 = *(const u16x4*)(&lt[cc * 68 + seg * 16]);
        u16x4 q1 = *(const u16x4*)(&lt[cc * 68 + seg * 16 + 4]);
        u16x4 q2 = *(const u16x4*)(&lt[cc * 68 + seg * 16 + 8]);
        u16x4 q3 = *(const u16x4*)(&lt[cc * 68 + seg * 16 + 12]);
        u16x8 o0, o1;
#pragma unroll
        for (int e = 0; e < 4; ++e) { o0[e] = q0[e]; o0[4 + e] = q1[e];
                                      o1[e] = q2[e]; o1[4 + e] = q3[e]; }
        unsigned short* dp = dstT + (size_t)(c0 + cc) * R + r0 + seg * 16;
        *(u16x8*)dp = o0;
        *(u16x8*)(dp + 8) = o1;
    }
}

// ---------------------------------------------------------------------------
// gemm_big_bf16: Ypart[bz][m][n] = A[m, kslice] @ B[kslice, n]
//   A bf16 row-major [m][k] (ld=NN), B bf16 transposed Bt[n=128][k=NN].
// split-K = 8, BM=BN=128, BK=64, block=256 (4 waves, 2x2).
// COUNTED-vmcnt double-buffer (T4, m218): tiles kt and kt+1 are always in
// flight; per K-step we wait vmcnt(8) (tile kt landed, kt+1 still flying),
// raw s_barrier (no drain!), MFMA, barrier, then issue tile kt+2 into the
// buffer just freed. Loads span both barriers -> HBM pipe never empties.
// XOR-swizzle on both sides (inverse-swizzled global source + swizzled
// ds_read_b128): fragment reads conflict-free.
// ---------------------------------------------------------------------------
__global__ __launch_bounds__(256, 2) void gemm_big_bf16(
        const unsigned short* __restrict__ A16,
        const unsigned short* __restrict__ Bt, float* __restrict__ Ypart) {
    __shared__ __align__(16) unsigned short LA[2 * 128 * 64];
    __shared__ __align__(16) unsigned short LB[2 * 128 * 64];
    int m0 = blockIdx.x * 128;
    int kbase = blockIdx.y * (NN / 8);
    int t = threadIdx.x;
    int w = t >> 6, lane = t & 63;
    int wy = w >> 1, wx = w & 1;
    int l15 = lane & 15, l4 = lane >> 4;
    int mrow = lane >> 3;                 // row within 8-row chunk (== m&7)
    int kj = ((lane & 7) ^ mrow) * 8;     // inverse-swizzled k offset (shorts)

    const unsigned short* ag[4];
    const unsigned short* bg[4];
    int lo[4];
#pragma unroll
    for (int i = 0; i < 4; ++i) {
        int chunk = i * 4 + w;            // 16 chunks of 8 rows
        int row = chunk * 8 + mrow;       // 0..127
        ag[i] = A16 + (size_t)(m0 + row) * NN + kbase + kj;
        bg[i] = Bt + (size_t)row * NN + kbase + kj;
        lo[i] = chunk * 512;              // wave-uniform LDS base (shorts)
    }
    floatx4 acc[4][4] = {};

    // prologue: stage tile 0 -> buf0, tile 1 -> buf1 (16 loads in flight)
#pragma unroll
    for (int i = 0; i < 4; ++i) { gld16(ag[i], &LA[lo[i]]); gld16(bg[i], &LB[lo[i]]); }
#pragma unroll
    for (int i = 0; i < 4; ++i) {
        gld16(ag[i] + 64, &LA[8192 + lo[i]]);
        gld16(bg[i] + 64, &LB[8192 + lo[i]]);
    }

    for (int kt = 0; kt < 16; ++kt) {
        // tile kt resident when only tile kt+1's 8 loads remain outstanding
        if (kt < 15) asm volatile("s_waitcnt vmcnt(8)" ::: "memory");
        else         asm volatile("s_waitcnt vmcnt(0)" ::: "memory");
        __builtin_amdgcn_s_barrier();     // raw barrier: NO vmcnt drain
        int cb = (kt & 1) << 13;          // *8192 shorts
#pragma unroll
        for (int ks = 0; ks < 2; ++ks) {
            s16x8 af[4], bfr[4];
#pragma unroll
            for (int i = 0; i < 4; ++i) {
                int m = wy * 64 + i * 16 + l15;
                int kb = ks * 4 + l4;
                af[i] = *(const s16x8*)(&LA[cb + m * 64 + ((kb ^ (m & 7)) * 8)]);
                int n = wx * 64 + i * 16 + l15;
                bfr[i] = *(const s16x8*)(&LB[cb + n * 64 + ((kb ^ (n & 7)) * 8)]);
            }
#pragma unroll
            for (int i = 0; i < 4; ++i)
#pragma unroll
                for (int j = 0; j < 4; ++j)
                    acc[i][j] = __builtin_amdgcn_mfma_f32_16x16x32_bf16(
                        af[i], bfr[j], acc[i][j], 0, 0, 0);
        }
        __builtin_amdgcn_s_barrier();     // all waves done reading buf (kt&1)
        if (kt < 14) {                    // refill freed buffer with tile kt+2
            int off = (kt + 2) * 64;
            int nb = (kt & 1) << 13;
#pragma unroll
            for (int i = 0; i < 4; ++i) {
                gld16(ag[i] + off, &LA[nb + lo[i]]);
                gld16(bg[i] + off, &LB[nb + lo[i]]);
            }
        }
    }
    float* Y = Ypart + (size_t)blockIdx.y * ((size_t)NN * DD);
#pragma unroll
    for (int i = 0; i < 4; ++i)
#pragma unroll
        for (int j = 0; j < 4; ++j) {
            int col = wx * 64 + j * 16 + l15;
#pragma unroll
            for (int r = 0; r < 4; ++r) {
                int row = wy * 64 + i * 16 + l4 * 4 + r;
                Y[(size_t)(m0 + row) * DD + col] = acc[i][j][r];
            }
        }
}

// ---------------------------------------------------------------------------
// gemm_big fallback (fp32 source), AMODE 1: fp32 row-major; AMODE 2: fp32
// [k][m] transposed staging. Only used when workspace is too small.
// ---------------------------------------------------------------------------
template <int AMODE>
__global__ __launch_bounds__(256, 2) void gemm_big(const void* __restrict__ Av,
        const unsigned short* __restrict__ Bt, float* __restrict__ Ypart) {
    __shared__ __align__(16) unsigned short LA[128 * 72];
    __shared__ __align__(16) unsigned short LB[128 * 72];
    int m0 = blockIdx.x * 128;
    int kbase = blockIdx.y * (NN / 8);
    int t = threadIdx.x;
    int wid = t >> 6, lane = t & 63;
    int wy = wid >> 1, wx = wid & 1;
    int l15 = lane & 15, l4 = lane >> 4;
    floatx4 acc[4][4] = {};

    for (int kt = 0; kt < NN / 8; kt += 64) {
        int k0 = kbase + kt;
        if (AMODE == 1) {
            const float* A32 = (const float*)Av;
            int m = t >> 4, kk = (t & 15) * 4;
#pragma unroll
            for (int s = 0; s < 8; ++s) {
                int mm = m + s * 16;
                floatx4 f = *(const floatx4*)(A32 + (size_t)(m0 + mm) * NN + k0 + kk);
                u16x4 pk;
#pragma unroll
                for (int e = 0; e < 4; ++e) pk[e] = f32_bf16(f[e]);
                *(u16x4*)(&LA[mm * 72 + kk]) = pk;
            }
        } else {
            const float* A32 = (const float*)Av;
            int kr = t >> 5, mm = (t & 31) * 4;
#pragma unroll
            for (int s = 0; s < 8; ++s) {
                int kk = kr + s * 8;
                floatx4 f = *(const floatx4*)(A32 + (size_t)(k0 + kk) * NN + m0 + mm);
#pragma unroll
                for (int e = 0; e < 4; ++e) LA[(mm + e) * 72 + kk] = f32_bf16(f[e]);
            }
        }
        {
            int n = t >> 3, kk = (t & 7) * 8;
#pragma unroll
            for (int s = 0; s < 4; ++s) {
                int nn = n + s * 32;
                u16x8 d = *(const u16x8*)(Bt + (size_t)nn * NN + k0 + kk);
                *(u16x8*)(&LB[nn * 72 + kk]) = d;
            }
        }
        __syncthreads();
#pragma unroll
        for (int ks = 0; ks < 2; ++ks) {
            s16x8 af[4], bfr[4];
#pragma unroll
            for (int i = 0; i < 4; ++i) {
                int m = wy * 64 + i * 16 + l15;
                af[i] = *(const s16x8*)(&LA[m * 72 + ks * 32 + l4 * 8]);
                int n = wx * 64 + i * 16 + l15;
                bfr[i] = *(const s16x8*)(&LB[n * 72 + ks * 32 + l4 * 8]);
            }
#pragma unroll
            for (int i = 0; i < 4; ++i)
#pragma unroll
                for (int j = 0; j < 4; ++j)
                    acc[i][j] = __builtin_amdgcn_mfma_f32_16x16x32_bf16(
                        af[i], bfr[j], acc[i][j], 0, 0, 0);
        }
        __syncthreads();
    }
    float* Y = Ypart + (size_t)blockIdx.y * ((size_t)NN * DD);
#pragma unroll
    for (int i = 0; i < 4; ++i)
#pragma unroll
        for (int j = 0; j < 4; ++j) {
            int col = wx * 64 + j * 16 + l15;
#pragma unroll
            for (int r = 0; r < 4; ++r) {
                int row = wy * 64 + i * 16 + l4 * 4 + r;
                Y[(size_t)(m0 + row) * DD + col] = acc[i][j][r];
            }
        }
}

// ---------------------------------------------------------------------------
// gemm_small: Z[m][n] = (sum_s Ypart[s][m][:]) @ W  * (1/sums[m])
//   writes out32 fp32 [NN][DD] (if non-null) and/or outT bf16 [DD][NN].
// BM=32, k=128 (one staged tile), grid = NN/32 = 256, block=256 (1 blk/CU).
// outT path transposes through LDS (stride 40 shorts = 80 B, 16-B aligned)
// so global stores are 16-B dense.
// ---------------------------------------------------------------------------
__global__ __launch_bounds__(256) void gemm_small(const float* __restrict__ Ypart,
        const unsigned short* __restrict__ Wt, const float* __restrict__ sums,
        float* __restrict__ out32, unsigned short* __restrict__ outT) {
    __shared__ __align__(16) unsigned short LA[128 * 40];   // staging [32*136] / LT [128*40]
    __shared__ __align__(16) unsigned short LB[128 * 136];
    int m0 = blockIdx.x * 32;
    int t = threadIdx.x;
    {
        int m = t >> 3, kk = (t & 7) * 4;
#pragma unroll
        for (int e = 0; e < 4; ++e) {
            floatx4 sum = {0.f, 0.f, 0.f, 0.f};
#pragma unroll
            for (int s = 0; s < 8; ++s)
                sum += *(const floatx4*)(Ypart + (size_t)s * ((size_t)NN * DD) +
                                         (size_t)(m0 + m) * DD + kk + e * 32);
            u16x4 pk;
#pragma unroll
            for (int e2 = 0; e2 < 4; ++e2) pk[e2] = f32_bf16(sum[e2]);
            *(u16x4*)(&LA[m * 136 + kk + e * 32]) = pk;
        }
        int n = t >> 1, k8 = (t & 1) * 64;
#pragma unroll
        for (int s = 0; s < 8; ++s)
            *(u16x8*)(&LB[n * 136 + k8 + s * 8]) =
                *(const u16x8*)(Wt + n * 128 + k8 + s * 8);
    }
    __syncthreads();
    int wid = t >> 6, lane = t & 63;
    int wy = wid >> 1, wx = wid & 1, l15 = lane & 15, l4 = lane >> 4;
    floatx4 acc[4] = {};
#pragma unroll
    for (int ks = 0; ks < 4; ++ks) {
        s16x8 af = *(const s16x8*)(&LA[(wy * 16 + l15) * 136 + ks * 32 + l4 * 8]);
#pragma unroll
        for (int j = 0; j < 4; ++j) {
            s16x8 bfr = *(const s16x8*)(&LB[(wx * 64 + j * 16 + l15) * 136 + ks * 32 + l4 * 8]);
            acc[j] = __builtin_amdgcn_mfma_f32_16x16x32_bf16(af, bfr, acc[j], 0, 0, 0);
        }
    }
    if (out32) {
#pragma unroll
        for (int j = 0; j < 4; ++j) {
            int col = wx * 64 + j * 16 + l15;
#pragma unroll
            for (int r = 0; r < 4; ++r) {
                int row = wy * 16 + l4 * 4 + r;
                int m = m0 + row;
                out32[(size_t)m * DD + col] = acc[j][r] / sums[m];
            }
        }
    }
    if (outT) {
        __syncthreads();                          // LA (af source) now dead
        unsigned short* LT = LA;                  // [128 cols][stride 40]
#pragma unroll
        for (int j = 0; j < 4; ++j) {
            int col = wx * 64 + j * 16 + l15;
#pragma unroll
            for (int r = 0; r < 4; ++r) {
                int row = wy * 16 + l4 * 4 + r;
                LT[col * 40 + row] = f32_bf16(acc[j][r] / sums[m0 + row]);
            }
        }
        __syncthreads();
        int col = t >> 1, half = t & 1;
        u16x8 v0 = *(const u16x8*)(&LT[col * 40 + half * 16]);
        u16x8 v1 = *(const u16x8*)(&LT[col * 40 + half * 16 + 8]);
        unsigned short* dp = outT + (size_t)col * NN + m0 + half * 16;
        *(u16x8*)dp = v0;
        *(u16x8*)(dp + 8) = v1;
    }
}

// ---------------------------------------------------------------------------
extern "C" void kernel_launch(void* const* d_in, const int* in_sizes, int n_in,
                              void* d_out, int out_size, void* d_ws, size_t ws_size,
                              hipStream_t stream) {
    const float* adj = (const float*)d_in[0];
    const float* uni = (const float*)d_in[1];
    const float* sub = (const float*)d_in[2];
    const float* ws1 = (const float*)d_in[3];
    const float* wu1 = (const float*)d_in[4];
    float* out = (float*)d_out;

    const size_t SZ_A16 = (size_t)NN * NN * 2;       // 128 MiB
    const size_t SZ_Y   = (size_t)8 * NN * DD * 4;   // 32 MiB (8 split-K slices)
    const size_t SZ_F   = (size_t)NN * DD * 2;       // 2 MiB
    const size_t SZ_W   = (size_t)128 * 128 * 2;
    const size_t SZ_V   = (size_t)NN * 4;

    size_t needA = 2 * SZ_A16 + SZ_Y + 6 * SZ_F + 2 * SZ_W + 2 * SZ_V;
    size_t needB = 1 * SZ_A16 + SZ_Y + 6 * SZ_F + 2 * SZ_W + 2 * SZ_V;
    int tier = (ws_size >= needA) ? 0 : ((ws_size >= needB) ? 1 : 2);

    char* p = (char*)d_ws;
    unsigned short* A16 = nullptr;
    unsigned short* AT16 = nullptr;
    if (tier == 0) { A16 = (unsigned short*)p; p += SZ_A16; }
    if (tier <= 1) { AT16 = (unsigned short*)p; p += SZ_A16; }
    float* Ypart = (float*)p; p += SZ_Y;
    unsigned short* F[6];
    for (int i = 0; i < 6; ++i) { F[i] = (unsigned short*)p; p += SZ_F; }
    unsigned short* Wst = (unsigned short*)p; p += SZ_W;
    unsigned short* Wut = (unsigned short*)p; p += SZ_W;
    float* rsum = (float*)p; p += SZ_V;
    float* csum = (float*)p; p += SZ_V;

    // --- preprocessing: one pass over adj does convert(s) + row/col sums ---
    // NOTE: convert grid is (x = C/64 column tiles, y = R/64 row tiles).
    hipMemsetAsync(rsum, 0, 2 * SZ_V, stream);   // rsum & csum contiguous
    if (tier == 0)
        convert_fused<<<dim3(128, 128), 256, 0, stream>>>(adj, AT16, A16, NN, NN, rsum, csum);
    else if (tier == 1)
        convert_fused<<<dim3(128, 128), 256, 0, stream>>>(adj, AT16, nullptr, NN, NN, rsum, csum);
    else
        convert_fused<<<dim3(128, 128), 256, 0, stream>>>(adj, nullptr, nullptr, NN, NN, rsum, csum);
    convert_fused<<<dim3(2, 128), 256, 0, stream>>>(uni, F[0], nullptr, NN, DD, nullptr, nullptr);
    convert_fused<<<dim3(2, 128), 256, 0, stream>>>(sub, F[1], nullptr, NN, DD, nullptr, nullptr);
    convert_fused<<<dim3(2, 2), 256, 0, stream>>>(ws1, Wst, nullptr, DD, DD, nullptr, nullptr);
    convert_fused<<<dim3(2, 2), 256, 0, stream>>>(wu1, Wut, nullptr, DD, DD, nullptr, nullptr);

    unsigned short* Ut[3] = {F[0], F[3], F[5]};
    unsigned short* St[3] = {F[1], F[2], F[4]};

    for (int pass = 0; pass < 3; ++pass) {
        // G2: Ys = adjT @ U_prev  (normalize by colsum, then @ w_s1)
        if (tier <= 1)
            gemm_big_bf16<<<dim3(64, 8), 256, 0, stream>>>(AT16, Ut[pass], Ypart);
        else
            gemm_big<2><<<dim3(64, 8), 256, 0, stream>>>(adj, Ut[pass], Ypart);
        if (pass < 2)
            gemm_small<<<256, 256, 0, stream>>>(Ypart, Wst, csum, nullptr, St[pass + 1]);
        else
            gemm_small<<<256, 256, 0, stream>>>(Ypart, Wst, csum, out, nullptr);

        // G1: Yu = adj @ S_prev  (normalize by rowsum, then @ w_u1)
        if (tier == 0)
            gemm_big_bf16<<<dim3(64, 8), 256, 0, stream>>>(A16, St[pass], Ypart);
        else
            gemm_big<1><<<dim3(64, 8), 256, 0, stream>>>(adj, St[pass], Ypart);
        if (pass < 2)
            gemm_small<<<256, 256, 0, stream>>>(Ypart, Wut, rsum, nullptr, Ut[pass + 1]);
        else
            gemm_small<<<256, 256, 0, stream>>>(Ypart, Wut, rsum, out + (size_t)NN * DD, nullptr);
    }
}